// Round 7
// baseline (736.688 us; speedup 1.0000x reference)
//
#include <hip/hip_runtime.h>
#include <hip/hip_fp16.h>

#define N_NODES 100000
#define N_EDGES 1600000
#define CH 128
#define OCH 64
#define NBUCKET 391   // ceil(100000/256) dst-buckets of 256 nodes
#define CAP 8192      // bucket capacity (mean 4092, sd ~64 -> 8192 is safe)
#define BIN_CHUNK 4096

typedef _Float16 half8 __attribute__((ext_vector_type(8)));
typedef float f32x4 __attribute__((ext_vector_type(4)));

__device__ __forceinline__ ushort f2h(float f) {
    _Float16 h = (_Float16)f;
    return *(ushort*)&h;
}

__device__ __forceinline__ uint pkadd(uint a, uint b) {
    __half2 r = __hadd2(*(__half2*)&a, *(__half2*)&b);
    return *(uint*)&r;
}

// XOR-swizzled f16 offset inside a [rows][128] f16 tile.
__device__ __forceinline__ int swz(int row, int k) {
    return row * 128 + ((((k >> 3) ^ (row & 15)) << 3) | (k & 7));
}

// ---------------- CSR build: LDS-staged counting sort ----------------

__global__ __launch_bounds__(512) void k_bin(const int* __restrict__ src,
                                             const int* __restrict__ dst,
                                             int* __restrict__ bfill,
                                             int* __restrict__ bin) {
    __shared__ int hist[512];
    __shared__ int wbase[512];
    __shared__ int cur[512];
    const int t = threadIdx.x;
    const int e0 = blockIdx.x * BIN_CHUNK;

    hist[t] = 0;
    __syncthreads();

    int ss[8], bb[8], dl[8];
#pragma unroll
    for (int j = 0; j < 8; ++j) {
        int e = e0 + j * 512 + t;
        bb[j] = -1;
        if (e < N_EDGES) {
            int s = src[e], d = dst[e];
            ss[j] = s; dl[j] = d & 255; bb[j] = d >> 8;
            atomicAdd(&hist[bb[j]], 1);
        }
    }
    __syncthreads();

    int v = hist[t];
    for (int off = 1; off < 512; off <<= 1) {
        int tv = (t >= off) ? hist[t - off] : 0;
        __syncthreads();
        hist[t] += tv;
        __syncthreads();
    }
    int excl = hist[t] - v;
    if (t < NBUCKET && v > 0) {
        int gb = atomicAdd(&bfill[t], v);
        wbase[t] = gb - excl;
    }
    cur[t] = excl;
    __syncthreads();

#pragma unroll
    for (int j = 0; j < 8; ++j) {
        if (bb[j] >= 0) {
            int p = atomicAdd(&cur[bb[j]], 1);
            bin[bb[j] * CAP + wbase[bb[j]] + p] = (ss[j] << 8) | dl[j];
        }
    }
}

__global__ void k_bscan(const int* __restrict__ bfill, int* __restrict__ bbase) {
    __shared__ int tmp[512];
    int t = threadIdx.x;
    int v = (t < NBUCKET) ? bfill[t] : 0;
    tmp[t] = v;
    __syncthreads();
    for (int off = 1; off < 512; off <<= 1) {
        int tv = (t >= off) ? tmp[t - off] : 0;
        __syncthreads();
        tmp[t] += tv;
        __syncthreads();
    }
    if (t < NBUCKET) bbase[t] = tmp[t] - v;
}

__global__ __launch_bounds__(256) void k_build(const int* __restrict__ bfill,
                                               const int* __restrict__ bbase,
                                               const int* __restrict__ bin,
                                               int* __restrict__ esrc,
                                               int* __restrict__ start,
                                               int* __restrict__ cnt,
                                               float* __restrict__ dis) {
    __shared__ int cnt_l[256];
    __shared__ int cur_l[256];
    __shared__ int sortbuf[CAP];
    const int t = threadIdx.x;
    const int b = blockIdx.x;
    const int n = bfill[b];
    const int base = bbase[b];
    const int* brec = bin + b * CAP;

    cnt_l[t] = 0;
    __syncthreads();
    for (int i = t; i < n; i += 256)
        atomicAdd(&cnt_l[brec[i] & 255], 1);
    __syncthreads();

    int v = cnt_l[t];
    for (int off = 1; off < 256; off <<= 1) {
        int tv = (t >= off) ? cnt_l[t - off] : 0;
        __syncthreads();
        cnt_l[t] += tv;
        __syncthreads();
    }
    int excl = cnt_l[t] - v;
    int node = b * 256 + t;
    if (node < N_NODES) {
        start[node] = base + excl;
        cnt[node] = v;
        dis[node] = rsqrtf((float)(v + 1));  // +1 self-loop
    }
    cur_l[t] = excl;
    __syncthreads();

    for (int i = t; i < n; i += 256) {
        int rec = brec[i];
        int p = atomicAdd(&cur_l[rec & 255], 1);
        sortbuf[p] = rec >> 8;
    }
    __syncthreads();
    for (int i = t; i < n; i += 256)
        esrc[base + i] = sortbuf[i];
}

// ---------------- weight prep (all three, one launch) ----------------

__global__ void k_prepW(const float* __restrict__ W1, const float* __restrict__ W2,
                        const float* __restrict__ Wo, ushort* __restrict__ W1s,
                        ushort* __restrict__ W2s, ushort* __restrict__ WoTs) {
    int i = blockIdx.x * blockDim.x + threadIdx.x;  // 0..40959
    if (i < 16384) {
        int k = i >> 7, n = i & 127;
        W1s[swz(n, k)] = f2h(W1[i]);
    } else if (i < 32768) {
        int j = i - 16384, k = j >> 7, n = j & 127;
        W2s[swz(n, k)] = f2h(W2[j]);
    } else if (i < 40960) {
        int j = i - 32768, k = j >> 6, n = j & 63;
        WoTs[swz(n, k)] = f2h(Wo[j]);
    }
}

// ---------------- MFMA GEMM: out_f16[r] = dis[r] * (A[r] @ W) ----------------

template <typename IT>
__global__ __launch_bounds__(256) void k_gemm_mfma(const IT* __restrict__ A,
                                                   const ushort* __restrict__ Ws,
                                                   const float* __restrict__ dis,
                                                   ushort* __restrict__ out) {
    __shared__ ushort sB[128 * 128];
    __shared__ ushort sA[64 * 128];
    const int tid = threadIdx.x;
    const int row0 = blockIdx.x * 64;

    for (int i = tid; i < 2048; i += 256)
        ((float4*)sB)[i] = ((const float4*)Ws)[i];

    for (int i = tid; i < 2048; i += 256) {
        int m = i >> 5, u = i & 31, k4 = u << 2;
        int r = row0 + m;
        ushort4 pk = make_ushort4(0, 0, 0, 0);
        if (r < N_NODES) {
            if constexpr (sizeof(IT) == 4) {
                float4 a = ((const float4*)A)[r * 32 + u];
                pk = make_ushort4(f2h(a.x), f2h(a.y), f2h(a.z), f2h(a.w));
            } else {
                pk = ((const ushort4*)A)[r * 32 + u];
            }
        }
        *(ushort4*)&sA[swz(m, k4)] = pk;
    }
    __syncthreads();

    const int lane = tid & 63, wv = tid >> 6;
    const int mrow = lane & 15, quad = lane >> 4;
    f32x4 acc[8] = {};
#pragma unroll
    for (int kc = 0; kc < 4; ++kc) {
        int g = kc * 4 + quad;
        half8 a = *(const half8*)&sA[(wv * 16 + mrow) * 128 + ((g ^ mrow) << 3)];
#pragma unroll
        for (int nt = 0; nt < 8; ++nt) {
            half8 b = *(const half8*)&sB[(nt * 16 + mrow) * 128 + ((g ^ mrow) << 3)];
            acc[nt] = __builtin_amdgcn_mfma_f32_16x16x32_f16(a, b, acc[nt], 0, 0, 0);
        }
    }

    const int rbase = row0 + wv * 16 + quad * 4;
    float ds[4];
#pragma unroll
    for (int rg = 0; rg < 4; ++rg)
        ds[rg] = (rbase + rg < N_NODES) ? dis[rbase + rg] : 0.f;
#pragma unroll
    for (int nt = 0; nt < 8; ++nt) {
#pragma unroll
        for (int rg = 0; rg < 4; ++rg) {
            int r = rbase + rg;
            if (r < N_NODES) out[r * 128 + nt * 16 + mrow] = f2h(acc[nt][rg] * ds[rg]);
        }
    }
}

// ---------------- CSR aggregation, XCD-channel-partitioned ----------------
// Block b: channel group g = b&7 (16 ch, 32 B) -> per-XCD h working set 3.2 MB,
// L2-resident (round-robin block->XCD). Wave per node; 8-lane sub-group per edge.

__global__ __launch_bounds__(256) void k_agg(const int* __restrict__ start,
                                             const int* __restrict__ cnt,
                                             const int* __restrict__ esrc,
                                             const ushort* __restrict__ h,
                                             const float* __restrict__ dis,
                                             const float* __restrict__ bias,
                                             ushort* __restrict__ out) {
    const int g = blockIdx.x & 7;               // channel group == target XCD
    const int tile = blockIdx.x >> 3;           // 25000 node-tiles of 4
    const int lane = threadIdx.x & 63;
    const int wv = threadIdx.x >> 6;
    const int v = tile * 4 + wv;
    const int sg = lane >> 3;                   // edge slot 0..7
    const int li = lane & 7;                    // channel lane (2 ch)
    const int cofs = g * 8 + li;                // uint offset within 64-uint row
    const uint* h32 = (const uint*)h;

    int n = cnt[v];
    const int* ep = esrc + start[v];

    uint accA = 0, accB = 0;
    int i = sg;
    for (; i + 8 < n; i += 16) {
        int s0 = ep[i], s1 = ep[i + 8];
        uint t0 = h32[s0 * 64 + cofs];
        uint t1 = h32[s1 * 64 + cofs];
        accA = pkadd(accA, t0);
        accB = pkadd(accB, t1);
    }
    if (i < n) {
        int s0 = ep[i];
        accA = pkadd(accA, h32[s0 * 64 + cofs]);
    }
    accA = pkadd(accA, accB);
    // reduce across the 8 edge slots
    accA = pkadd(accA, (uint)__shfl_xor((int)accA, 8));
    accA = pkadd(accA, (uint)__shfl_xor((int)accA, 16));
    accA = pkadd(accA, (uint)__shfl_xor((int)accA, 32));

    if (sg == 0) {
        uint hv = h32[v * 64 + cofs];            // self-loop term h'[v]
        accA = pkadd(accA, hv);
        float s = dis[v];
        float2 a = __half22float2(*(__half2*)&accA);
        float2 bv = ((const float2*)bias)[g * 8 + li];
        a.x = fmaxf(a.x * s + bv.x, 0.f);
        a.y = fmaxf(a.y * s + bv.y, 0.f);
        __half2 o = __float22half2_rn(a);
        ((uint*)out)[v * 64 + cofs] = *(uint*)&o;
    }
}

// ---------------- final MFMA: out_f32[N][64] = (x1+x2)@Wo + bo ----------------

__global__ __launch_bounds__(256) void k_final_mfma(const ushort* __restrict__ x1,
                                                    const ushort* __restrict__ x2,
                                                    const ushort* __restrict__ Ws,
                                                    const float* __restrict__ bo,
                                                    float* __restrict__ out) {
    __shared__ ushort sB[64 * 128];
    __shared__ ushort sA[64 * 128];
    const int tid = threadIdx.x;
    const int row0 = blockIdx.x * 64;

    for (int i = tid; i < 1024; i += 256)
        ((float4*)sB)[i] = ((const float4*)Ws)[i];

    for (int i = tid; i < 2048; i += 256) {
        int m = i >> 5, u = i & 31, k4 = u << 2;
        int r = row0 + m;
        uint2 pk = make_uint2(0, 0);
        if (r < N_NODES) {
            uint2 ua = ((const uint2*)x1)[r * 32 + u];
            uint2 ub = ((const uint2*)x2)[r * 32 + u];
            __half2 s0 = __hadd2(*(__half2*)&ua.x, *(__half2*)&ub.x);
            __half2 s1 = __hadd2(*(__half2*)&ua.y, *(__half2*)&ub.y);
            pk = make_uint2(*(uint*)&s0, *(uint*)&s1);
        }
        *(uint2*)&sA[swz(m, k4)] = pk;
    }
    __syncthreads();

    const int lane = tid & 63, wv = tid >> 6;
    const int mrow = lane & 15, quad = lane >> 4;
    f32x4 acc[4] = {};
#pragma unroll
    for (int kc = 0; kc < 4; ++kc) {
        int g = kc * 4 + quad;
        half8 a = *(const half8*)&sA[(wv * 16 + mrow) * 128 + ((g ^ mrow) << 3)];
#pragma unroll
        for (int nt = 0; nt < 4; ++nt) {
            half8 b = *(const half8*)&sB[(nt * 16 + mrow) * 128 + ((g ^ mrow) << 3)];
            acc[nt] = __builtin_amdgcn_mfma_f32_16x16x32_f16(a, b, acc[nt], 0, 0, 0);
        }
    }

    const int rbase = row0 + wv * 16 + quad * 4;
#pragma unroll
    for (int nt = 0; nt < 4; ++nt) {
        float bb = bo[nt * 16 + mrow];
#pragma unroll
        for (int rg = 0; rg < 4; ++rg) {
            int r = rbase + rg;
            if (r < N_NODES) out[(size_t)r * 64 + nt * 16 + mrow] = acc[nt][rg] + bb;
        }
    }
}

// ---------------- launch ----------------

extern "C" void kernel_launch(void* const* d_in, const int* in_sizes, int n_in,
                              void* d_out, int out_size, void* d_ws, size_t ws_size,
                              hipStream_t stream) {
    const float* x  = (const float*)d_in[0];
    const int*   ei = (const int*)d_in[1];
    const int*   src = ei;
    const int*   dst = ei + N_EDGES;
    const float* W1 = (const float*)d_in[2];
    const float* b1 = (const float*)d_in[3];
    const float* W2 = (const float*)d_in[4];
    const float* b2 = (const float*)d_in[5];
    const float* Wo = (const float*)d_in[6];
    const float* bo = (const float*)d_in[7];
    float* out = (float*)d_out;

    char* ws = (char*)d_ws;
    int*    bfill  = (int*)ws;            ws += 2048;
    int*    bbase  = (int*)ws;            ws += 2048;
    int*    cnt    = (int*)ws;            ws += 400000;
    int*    start  = (int*)ws;            ws += 400000;
    float*  dis    = (float*)ws;          ws += 400000;
    int*    bin    = (int*)ws;            ws += (size_t)NBUCKET * CAP * 4;
    int*    esrc   = (int*)ws;            ws += (size_t)N_EDGES * 4;
    ushort* W1s    = (ushort*)ws;         ws += 32768;
    ushort* W2s    = (ushort*)ws;         ws += 32768;
    ushort* WoTs   = (ushort*)ws;         ws += 16384;
    ushort* h      = (ushort*)ws;         ws += (size_t)N_NODES * CH * 2;
    ushort* x1     = (ushort*)ws;         ws += (size_t)N_NODES * CH * 2;
    ushort* x2     = (ushort*)ws;

    const int B = 256;
    const int gG = (N_NODES + 63) / 64;   // 1563
    const int gA = (N_NODES / 4) * 8;     // 200000: 8 channel groups x 25000 tiles

    // CSR build (LDS-staged counting sort) + weight prep
    hipMemsetAsync(bfill, 0, 2048, stream);
    k_bin<<<(N_EDGES + BIN_CHUNK - 1) / BIN_CHUNK, 512, 0, stream>>>(src, dst, bfill, bin);
    k_bscan<<<1, 512, 0, stream>>>(bfill, bbase);
    k_build<<<NBUCKET, 256, 0, stream>>>(bfill, bbase, bin, esrc, start, cnt, dis);
    k_prepW<<<160, B, 0, stream>>>(W1, W2, Wo, W1s, W2s, WoTs);

    // layer 1
    k_gemm_mfma<float><<<gG, B, 0, stream>>>(x, W1s, dis, h);
    k_agg<<<gA, B, 0, stream>>>(start, cnt, esrc, h, dis, b1, x1);

    // layer 2
    k_gemm_mfma<ushort><<<gG, B, 0, stream>>>(x1, W2s, dis, h);
    k_agg<<<gA, B, 0, stream>>>(start, cnt, esrc, h, dis, b2, x2);

    // output projection
    k_final_mfma<<<gG, B, 0, stream>>>(x1, x2, WoTs, bo, out);
}

// Round 8
// 373.649 us; speedup vs baseline: 1.9716x; 1.9716x over previous
//
#include <hip/hip_runtime.h>
#include <hip/hip_fp16.h>

#define N_NODES 100000
#define N_EDGES 1600000
#define CH 128
#define OCH 64
#define NBUCKET 391   // ceil(100000/256) dst-buckets of 256 nodes
#define CAP 8192      // bucket capacity (mean 4092, sd ~64 -> 8192 is safe)
#define BIN_CHUNK 4096
#define ROWU 136      // padded row stride in ushorts (128 + 8): 2-way LDS conflicts only

typedef _Float16 half8 __attribute__((ext_vector_type(8)));
typedef float f32x4 __attribute__((ext_vector_type(4)));

__device__ __forceinline__ ushort f2h(float f) {
    _Float16 h = (_Float16)f;
    return *(ushort*)&h;
}

__device__ __forceinline__ uint pkadd(uint a, uint b) {
    __half2 r = __hadd2(*(__half2*)&a, *(__half2*)&b);
    return *(uint*)&r;
}

// ---------------- CSR build: LDS-staged counting sort ----------------

__global__ __launch_bounds__(512) void k_bin(const int* __restrict__ src,
                                             const int* __restrict__ dst,
                                             int* __restrict__ bfill,
                                             int* __restrict__ bin) {
    __shared__ int hist[512];
    __shared__ int wbase[512];
    __shared__ int cur[512];
    const int t = threadIdx.x;
    const int e0 = blockIdx.x * BIN_CHUNK;

    hist[t] = 0;
    __syncthreads();

    int ss[8], bb[8], dl[8];
#pragma unroll
    for (int j = 0; j < 8; ++j) {
        int e = e0 + j * 512 + t;
        bb[j] = -1;
        if (e < N_EDGES) {
            int s = src[e], d = dst[e];
            ss[j] = s; dl[j] = d & 255; bb[j] = d >> 8;
            atomicAdd(&hist[bb[j]], 1);
        }
    }
    __syncthreads();

    int v = hist[t];
    for (int off = 1; off < 512; off <<= 1) {
        int tv = (t >= off) ? hist[t - off] : 0;
        __syncthreads();
        hist[t] += tv;
        __syncthreads();
    }
    int excl = hist[t] - v;
    if (t < NBUCKET && v > 0) {
        int gb = atomicAdd(&bfill[t], v);
        wbase[t] = gb - excl;
    }
    cur[t] = excl;
    __syncthreads();

#pragma unroll
    for (int j = 0; j < 8; ++j) {
        if (bb[j] >= 0) {
            int p = atomicAdd(&cur[bb[j]], 1);
            bin[bb[j] * CAP + wbase[bb[j]] + p] = (ss[j] << 8) | dl[j];
        }
    }
}

__global__ void k_bscan(const int* __restrict__ bfill, int* __restrict__ bbase) {
    __shared__ int tmp[512];
    int t = threadIdx.x;
    int v = (t < NBUCKET) ? bfill[t] : 0;
    tmp[t] = v;
    __syncthreads();
    for (int off = 1; off < 512; off <<= 1) {
        int tv = (t >= off) ? tmp[t - off] : 0;
        __syncthreads();
        tmp[t] += tv;
        __syncthreads();
    }
    if (t < NBUCKET) bbase[t] = tmp[t] - v;
}

__global__ __launch_bounds__(256) void k_build(const int* __restrict__ bfill,
                                               const int* __restrict__ bbase,
                                               const int* __restrict__ bin,
                                               int* __restrict__ esrc,
                                               int* __restrict__ start,
                                               int* __restrict__ cnt,
                                               float* __restrict__ dis) {
    __shared__ int cnt_l[256];
    __shared__ int cur_l[256];
    __shared__ int sortbuf[CAP];
    const int t = threadIdx.x;
    const int b = blockIdx.x;
    const int n = bfill[b];
    const int base = bbase[b];
    const int* brec = bin + b * CAP;

    cnt_l[t] = 0;
    __syncthreads();
    for (int i = t; i < n; i += 256)
        atomicAdd(&cnt_l[brec[i] & 255], 1);
    __syncthreads();

    int v = cnt_l[t];
    for (int off = 1; off < 256; off <<= 1) {
        int tv = (t >= off) ? cnt_l[t - off] : 0;
        __syncthreads();
        cnt_l[t] += tv;
        __syncthreads();
    }
    int excl = cnt_l[t] - v;
    int node = b * 256 + t;
    if (node < N_NODES) {
        start[node] = base + excl;
        cnt[node] = v;
        dis[node] = rsqrtf((float)(v + 1));  // +1 self-loop
    }
    cur_l[t] = excl;
    __syncthreads();

    for (int i = t; i < n; i += 256) {
        int rec = brec[i];
        int p = atomicAdd(&cur_l[rec & 255], 1);
        sortbuf[p] = rec >> 8;
    }
    __syncthreads();
    for (int i = t; i < n; i += 256)
        esrc[base + i] = sortbuf[i];
}

// ---------------- weight prep: W[k][n] f32 -> padded W^T f16 images ----------------

__global__ void k_prepW(const float* __restrict__ W1, const float* __restrict__ W2,
                        const float* __restrict__ Wo, ushort* __restrict__ W1p,
                        ushort* __restrict__ W2p, ushort* __restrict__ Wop) {
    int i = blockIdx.x * blockDim.x + threadIdx.x;  // 0..40959
    if (i < 16384) {
        int k = i >> 7, n = i & 127;
        W1p[n * ROWU + k] = f2h(W1[i]);
    } else if (i < 32768) {
        int j = i - 16384, k = j >> 7, n = j & 127;
        W2p[n * ROWU + k] = f2h(W2[j]);
    } else if (i < 40960) {
        int j = i - 32768, k = j >> 6, n = j & 63;
        Wop[n * ROWU + k] = f2h(Wo[j]);
    }
}

// ---------------- GEMM1: h[r] = f16(dis[r] * (x[r] @ W1)), x f32 ----------------

__global__ __launch_bounds__(256) void k_gemm1(const float* __restrict__ A,
                                               const ushort* __restrict__ Wp,
                                               const float* __restrict__ dis,
                                               ushort* __restrict__ out) {
    __shared__ ushort sB[128 * ROWU];
    __shared__ ushort sA[64 * ROWU];
    const int tid = threadIdx.x;
    const int row0 = blockIdx.x * 64;

    for (int i = tid; i < 128 * ROWU / 8; i += 256)  // 2176 float4s = 34816 B
        ((float4*)sB)[i] = ((const float4*)Wp)[i];

    for (int i = tid; i < 2048; i += 256) {  // 64 rows x 32 4-elem units
        int m = i >> 5, u = i & 31;
        int r = row0 + m;
        ushort4 pk = make_ushort4(0, 0, 0, 0);
        if (r < N_NODES) {
            float4 a = ((const float4*)A)[r * 32 + u];
            pk = make_ushort4(f2h(a.x), f2h(a.y), f2h(a.z), f2h(a.w));
        }
        *(ushort4*)&sA[m * ROWU + u * 4] = pk;
    }
    __syncthreads();

    const int lane = tid & 63, wv = tid >> 6;
    const int mrow = lane & 15, quad = lane >> 4;
    f32x4 acc[8] = {};
#pragma unroll
    for (int kc = 0; kc < 4; ++kc) {
        half8 a = *(const half8*)&sA[(wv * 16 + mrow) * ROWU + kc * 32 + quad * 8];
#pragma unroll
        for (int nt = 0; nt < 8; ++nt) {
            half8 b = *(const half8*)&sB[(nt * 16 + mrow) * ROWU + kc * 32 + quad * 8];
            acc[nt] = __builtin_amdgcn_mfma_f32_16x16x32_f16(a, b, acc[nt], 0, 0, 0);
        }
    }

    const int rbase = row0 + wv * 16 + quad * 4;
    float ds[4];
#pragma unroll
    for (int rg = 0; rg < 4; ++rg)
        ds[rg] = (rbase + rg < N_NODES) ? dis[rbase + rg] : 0.f;
#pragma unroll
    for (int nt = 0; nt < 8; ++nt) {
#pragma unroll
        for (int rg = 0; rg < 4; ++rg) {
            int r = rbase + rg;
            if (r < N_NODES) out[r * 128 + nt * 16 + mrow] = f2h(acc[nt][rg] * ds[rg]);
        }
    }
}

// ---------------- aggregation core (r6-proven): one wave, one node ----------------
// returns (half==0, lanes 0..31): uint2 = 4 channels of sum_e h'[src_e] + h'[v]

__device__ __forceinline__ uint2 agg_node(int v, const int* __restrict__ cnt,
                                          const int* __restrict__ start,
                                          const int* __restrict__ esrc,
                                          const uint2* __restrict__ h4,
                                          int half, int l) {
    int n = cnt[v];
    const int* ep = esrc + start[v];
    uint2 accA = make_uint2(0, 0), accB = make_uint2(0, 0);
    int i = half;
    for (; i + 7 < n; i += 8) {
        int s0 = ep[i], s1 = ep[i + 2], s2 = ep[i + 4], s3 = ep[i + 6];
        uint2 t0 = h4[s0 * 32 + l];
        uint2 t1 = h4[s1 * 32 + l];
        uint2 t2 = h4[s2 * 32 + l];
        uint2 t3 = h4[s3 * 32 + l];
        accA.x = pkadd(accA.x, t0.x); accA.y = pkadd(accA.y, t0.y);
        accB.x = pkadd(accB.x, t1.x); accB.y = pkadd(accB.y, t1.y);
        accA.x = pkadd(accA.x, t2.x); accA.y = pkadd(accA.y, t2.y);
        accB.x = pkadd(accB.x, t3.x); accB.y = pkadd(accB.y, t3.y);
    }
    for (; i < n; i += 2) {
        int s0 = ep[i];
        uint2 t0 = h4[s0 * 32 + l];
        accA.x = pkadd(accA.x, t0.x); accA.y = pkadd(accA.y, t0.y);
    }
    accA.x = pkadd(accA.x, accB.x);
    accA.y = pkadd(accA.y, accB.y);
    accA.x = pkadd(accA.x, (uint)__shfl_xor((int)accA.x, 32));
    accA.y = pkadd(accA.y, (uint)__shfl_xor((int)accA.y, 32));
    if (half == 0) {
        uint2 hv = h4[v * 32 + l];  // self-loop term h'[v]
        accA.x = pkadd(accA.x, hv.x);
        accA.y = pkadd(accA.y, hv.y);
    }
    return accA;
}

// ---------------- aggB: x1 = relu(dis*agg(h)+b1); h2 = dis*(x1@W2) ----------------
// block = 16 nodes (4 waves x 4 nodes), then one 16-row MFMA tile over W2.

__global__ __launch_bounds__(256) void k_aggB(const int* __restrict__ start,
                                              const int* __restrict__ cnt,
                                              const int* __restrict__ esrc,
                                              const ushort* __restrict__ h,
                                              const float* __restrict__ dis,
                                              const float* __restrict__ b1,
                                              const ushort* __restrict__ W2p,
                                              ushort* __restrict__ x1,
                                              ushort* __restrict__ h2) {
    __shared__ ushort sW[128 * ROWU];  // 34816 B
    __shared__ ushort sS[16 * ROWU];   // 4352 B
    const int tid = threadIdx.x;
    const int v0 = blockIdx.x * 16;
    const int lane = tid & 63, wv = tid >> 6;
    const int half = lane >> 5, l = lane & 31;
    const uint2* h4 = (const uint2*)h;

    for (int i = tid; i < 128 * ROWU / 8; i += 256)
        ((float4*)sW)[i] = ((const float4*)W2p)[i];

    for (int j = 0; j < 4; ++j) {
        int v = v0 + wv * 4 + j;
        uint2 acc = agg_node(v, cnt, start, esrc, h4, half, l);
        if (half == 0) {
            float s = dis[v];
            float2 a0 = __half22float2(*(__half2*)&acc.x);
            float2 a1 = __half22float2(*(__half2*)&acc.y);
            float4 bv = ((const float4*)b1)[l];
            a0.x = fmaxf(a0.x * s + bv.x, 0.f);
            a0.y = fmaxf(a0.y * s + bv.y, 0.f);
            a1.x = fmaxf(a1.x * s + bv.z, 0.f);
            a1.y = fmaxf(a1.y * s + bv.w, 0.f);
            __half2 o0 = __float22half2_rn(make_float2(a0.x, a0.y));
            __half2 o1 = __float22half2_rn(make_float2(a1.x, a1.y));
            uint2 ov = make_uint2(*(uint*)&o0, *(uint*)&o1);
            ((uint2*)x1)[v * 32 + l] = ov;
            *(uint2*)&sS[(wv * 4 + j) * ROWU + l * 4] = ov;
        }
    }
    __syncthreads();

    // MFMA: wave wv -> cols [wv*32, wv*32+32)
    const int mrow = lane & 15, quad = lane >> 4;
    f32x4 acc[2] = {};
#pragma unroll
    for (int kc = 0; kc < 4; ++kc) {
        half8 a = *(const half8*)&sS[mrow * ROWU + kc * 32 + quad * 8];
#pragma unroll
        for (int t = 0; t < 2; ++t) {
            int nt = wv * 2 + t;
            half8 b = *(const half8*)&sW[(nt * 16 + mrow) * ROWU + kc * 32 + quad * 8];
            acc[t] = __builtin_amdgcn_mfma_f32_16x16x32_f16(a, b, acc[t], 0, 0, 0);
        }
    }
    const int rbase = v0 + quad * 4;
    float ds[4];
#pragma unroll
    for (int rg = 0; rg < 4; ++rg) ds[rg] = dis[rbase + rg];
#pragma unroll
    for (int t = 0; t < 2; ++t) {
        int col = (wv * 2 + t) * 16 + mrow;
#pragma unroll
        for (int rg = 0; rg < 4; ++rg)
            h2[(rbase + rg) * 128 + col] = f2h(acc[t][rg] * ds[rg]);
    }
}

// ---------------- aggC: s = x1 + relu(dis*agg(h2)+b2); out = s@Wo + bo ----------------

__global__ __launch_bounds__(256) void k_aggC(const int* __restrict__ start,
                                              const int* __restrict__ cnt,
                                              const int* __restrict__ esrc,
                                              const ushort* __restrict__ h2,
                                              const float* __restrict__ dis,
                                              const float* __restrict__ b2,
                                              const ushort* __restrict__ x1,
                                              const ushort* __restrict__ Wop,
                                              const float* __restrict__ bo,
                                              float* __restrict__ out) {
    __shared__ ushort sW[64 * ROWU];  // 17408 B
    __shared__ ushort sS[16 * ROWU];  // 4352 B
    const int tid = threadIdx.x;
    const int v0 = blockIdx.x * 16;
    const int lane = tid & 63, wv = tid >> 6;
    const int half = lane >> 5, l = lane & 31;
    const uint2* h4 = (const uint2*)h2;

    for (int i = tid; i < 64 * ROWU / 8; i += 256)
        ((float4*)sW)[i] = ((const float4*)Wop)[i];

    for (int j = 0; j < 4; ++j) {
        int v = v0 + wv * 4 + j;
        uint2 acc = agg_node(v, cnt, start, esrc, h4, half, l);
        if (half == 0) {
            float s = dis[v];
            float2 a0 = __half22float2(*(__half2*)&acc.x);
            float2 a1 = __half22float2(*(__half2*)&acc.y);
            float4 bv = ((const float4*)b2)[l];
            a0.x = fmaxf(a0.x * s + bv.x, 0.f);
            a0.y = fmaxf(a0.y * s + bv.y, 0.f);
            a1.x = fmaxf(a1.x * s + bv.z, 0.f);
            a1.y = fmaxf(a1.y * s + bv.w, 0.f);
            __half2 o0 = __float22half2_rn(make_float2(a0.x, a0.y));
            __half2 o1 = __float22half2_rn(make_float2(a1.x, a1.y));
            uint2 xv = ((const uint2*)x1)[v * 32 + l];  // s = x1 + x2 (fp16)
            uint2 ov = make_uint2(pkadd(*(uint*)&o0, xv.x), pkadd(*(uint*)&o1, xv.y));
            *(uint2*)&sS[(wv * 4 + j) * ROWU + l * 4] = ov;
        }
    }
    __syncthreads();

    // MFMA: wave wv -> cols [wv*16, wv*16+16)
    const int mrow = lane & 15, quad = lane >> 4;
    f32x4 acc = {};
#pragma unroll
    for (int kc = 0; kc < 4; ++kc) {
        half8 a = *(const half8*)&sS[mrow * ROWU + kc * 32 + quad * 8];
        half8 b = *(const half8*)&sW[(wv * 16 + mrow) * ROWU + kc * 32 + quad * 8];
        acc = __builtin_amdgcn_mfma_f32_16x16x32_f16(a, b, acc, 0, 0, 0);
    }
    const int col = wv * 16 + mrow;
    const int rbase = v0 + quad * 4;
    float bb = bo[col];
#pragma unroll
    for (int rg = 0; rg < 4; ++rg)
        out[(size_t)(rbase + rg) * 64 + col] = acc[rg] + bb;
}

// ---------------- launch ----------------

extern "C" void kernel_launch(void* const* d_in, const int* in_sizes, int n_in,
                              void* d_out, int out_size, void* d_ws, size_t ws_size,
                              hipStream_t stream) {
    const float* x  = (const float*)d_in[0];
    const int*   ei = (const int*)d_in[1];
    const int*   src = ei;
    const int*   dst = ei + N_EDGES;
    const float* W1 = (const float*)d_in[2];
    const float* b1 = (const float*)d_in[3];
    const float* W2 = (const float*)d_in[4];
    const float* b2 = (const float*)d_in[5];
    const float* Wo = (const float*)d_in[6];
    const float* bo = (const float*)d_in[7];
    float* out = (float*)d_out;

    char* ws = (char*)d_ws;
    int*    bfill  = (int*)ws;            ws += 2048;
    int*    bbase  = (int*)ws;            ws += 2048;
    int*    cnt    = (int*)ws;            ws += 400000;
    int*    start  = (int*)ws;            ws += 400000;
    float*  dis    = (float*)ws;          ws += 400000;
    int*    bin    = (int*)ws;            ws += (size_t)NBUCKET * CAP * 4;
    int*    esrc   = (int*)ws;            ws += (size_t)N_EDGES * 4;
    ushort* W1p    = (ushort*)ws;         ws += 128 * ROWU * 2;  // 34816
    ushort* W2p    = (ushort*)ws;         ws += 128 * ROWU * 2;
    ushort* Wop    = (ushort*)ws;         ws += 64 * ROWU * 2;   // 17408
    ushort* h      = (ushort*)ws;         ws += (size_t)N_NODES * CH * 2;
    ushort* x1     = (ushort*)ws;         ws += (size_t)N_NODES * CH * 2;
    ushort* h2     = (ushort*)ws;

    const int B = 256;
    const int gG = (N_NODES + 63) / 64;   // 1563
    const int gA = N_NODES / 16;          // 6250

    // CSR build (LDS-staged counting sort) + weight prep
    hipMemsetAsync(bfill, 0, 2048, stream);
    k_bin<<<(N_EDGES + BIN_CHUNK - 1) / BIN_CHUNK, 512, 0, stream>>>(src, dst, bfill, bin);
    k_bscan<<<1, 512, 0, stream>>>(bfill, bbase);
    k_build<<<NBUCKET, 256, 0, stream>>>(bfill, bbase, bin, esrc, start, cnt, dis);
    k_prepW<<<160, B, 0, stream>>>(W1, W2, Wo, W1p, W2p, Wop);

    // layer 1 GEMM
    k_gemm1<<<gG, B, 0, stream>>>(x, W1p, dis, h);
    // agg1 + GEMM2 fused
    k_aggB<<<gA, B, 0, stream>>>(start, cnt, esrc, h, dis, b1, W2p, x1, h2);
    // agg2 + output projection fused
    k_aggC<<<gA, B, 0, stream>>>(start, cnt, esrc, h2, dis, b2, x1, Wop, bo, out);
}

// Round 9
// 356.715 us; speedup vs baseline: 2.0652x; 1.0475x over previous
//
#include <hip/hip_runtime.h>
#include <hip/hip_fp16.h>

#define N_NODES 100000
#define N_EDGES 1600000
#define CH 128
#define OCH 64
#define NBUCKET 98     // ceil(100000/1024) dst-buckets of 1024 nodes
#define CAP 18432      // bucket capacity (mean 16327, sd ~128 -> +16σ safe)
#define BIN_CHUNK 4096

typedef _Float16 half8 __attribute__((ext_vector_type(8)));
typedef float f32x4 __attribute__((ext_vector_type(4)));

__device__ __forceinline__ ushort f2h(float f) {
    _Float16 h = (_Float16)f;
    return *(ushort*)&h;
}

__device__ __forceinline__ uint pkadd(uint a, uint b) {
    __half2 r = __hadd2(*(__half2*)&a, *(__half2*)&b);
    return *(uint*)&r;
}

// XOR-swizzled f16 offset inside a [rows][128] f16 tile (r6-proven, 0 conflicts).
__device__ __forceinline__ int swz(int row, int k) {
    return row * 128 + ((((k >> 3) ^ (row & 15)) << 3) | (k & 7));
}

// ---------------- CSR build: LDS-staged counting sort, 1024-node buckets ----------------
// rec = (src << 10) | (dst & 1023); bucket = dst >> 10. src < 2^22 fits.

__global__ __launch_bounds__(512) void k_bin(const int* __restrict__ src,
                                             const int* __restrict__ dst,
                                             int* __restrict__ bfill,
                                             int* __restrict__ bin) {
    __shared__ int hist[128];
    __shared__ int wbase[128];
    __shared__ int cur[128];
    const int t = threadIdx.x;
    const int e0 = blockIdx.x * BIN_CHUNK;

    if (t < 128) hist[t] = 0;
    __syncthreads();

    int rec[8], bb[8];
#pragma unroll
    for (int j = 0; j < 8; ++j) {
        int e = e0 + j * 512 + t;
        bb[j] = -1;
        if (e < N_EDGES) {
            int s = src[e], d = dst[e];
            rec[j] = (s << 10) | (d & 1023);
            bb[j] = d >> 10;
            atomicAdd(&hist[bb[j]], 1);
        }
    }
    __syncthreads();

    int v = (t < 128) ? hist[t] : 0;
    for (int off = 1; off < 128; off <<= 1) {
        int tv = (t >= off && t < 128) ? hist[t - off] : 0;
        __syncthreads();
        if (t < 128) hist[t] += tv;
        __syncthreads();
    }
    int excl = (t < 128) ? (hist[t] - v) : 0;
    if (t < NBUCKET && v > 0) {
        int gb = atomicAdd(&bfill[t], v);
        wbase[t] = gb - excl;
    }
    if (t < 128) cur[t] = excl;
    __syncthreads();

#pragma unroll
    for (int j = 0; j < 8; ++j) {
        if (bb[j] >= 0) {
            int p = atomicAdd(&cur[bb[j]], 1);
            bin[bb[j] * CAP + wbase[bb[j]] + p] = rec[j];
        }
    }
}

// One block per bucket: per-node count+scan in LDS, reorder, stream out coalesced.
// Each block redundantly scans the 98 bucket fills (k_bscan folded in).
__global__ __launch_bounds__(256) void k_build(const int* __restrict__ bfill,
                                               const int* __restrict__ bin,
                                               int* __restrict__ esrc,
                                               int* __restrict__ start,
                                               int* __restrict__ cnt,
                                               float* __restrict__ dis) {
    __shared__ int cnt_l[1024];
    __shared__ int cur_l[1024];
    __shared__ int tsum[256];
    __shared__ int bs[128];
    __shared__ int sortbuf[CAP];
    const int t = threadIdx.x;
    const int b = blockIdx.x;
    const int n = bfill[b];
    const int* brec = bin + b * CAP;

    // cross-bucket inclusive scan of fills (tiny, redundant per block)
    if (t < 128) bs[t] = (t < NBUCKET) ? bfill[t] : 0;
    __syncthreads();
    {
        int v = (t < 128) ? bs[t] : 0;
        for (int off = 1; off < 128; off <<= 1) {
            int tv = (t >= off && t < 128) ? bs[t - off] : 0;
            __syncthreads();
            if (t < 128) bs[t] += tv;
            __syncthreads();
        }
    }
    const int base = bs[b] - n;  // exclusive bucket base == CSR base of node b*1024

    cnt_l[t] = 0; cnt_l[t + 256] = 0; cnt_l[t + 512] = 0; cnt_l[t + 768] = 0;
    __syncthreads();
    for (int i = t; i < n; i += 256)
        atomicAdd(&cnt_l[brec[i] & 1023], 1);
    __syncthreads();

    // scan 1024 counts: 4 per thread + 256-thread Hillis-Steele
    int c0 = cnt_l[t * 4], c1 = cnt_l[t * 4 + 1], c2 = cnt_l[t * 4 + 2], c3 = cnt_l[t * 4 + 3];
    int s = c0 + c1 + c2 + c3;
    tsum[t] = s;
    __syncthreads();
    for (int off = 1; off < 256; off <<= 1) {
        int tv = (t >= off) ? tsum[t - off] : 0;
        __syncthreads();
        tsum[t] += tv;
        __syncthreads();
    }
    int e0 = tsum[t] - s;  // bucket-local exclusive for node t*4
    int e1 = e0 + c0, e2 = e1 + c1, e3 = e2 + c2;
    cur_l[t * 4] = e0; cur_l[t * 4 + 1] = e1; cur_l[t * 4 + 2] = e2; cur_l[t * 4 + 3] = e3;
    int node0 = b * 1024 + t * 4;
    int ee[4] = {e0, e1, e2, e3};
    int cc[4] = {c0, c1, c2, c3};
#pragma unroll
    for (int j = 0; j < 4; ++j) {
        int node = node0 + j;
        if (node < N_NODES) {
            start[node] = base + ee[j];
            cnt[node] = cc[j];
            dis[node] = rsqrtf((float)(cc[j] + 1));  // +1 self-loop
        }
    }
    __syncthreads();

    for (int i = t; i < n; i += 256) {
        int rec = brec[i];
        int p = atomicAdd(&cur_l[rec & 1023], 1);
        sortbuf[p] = rec >> 10;
    }
    __syncthreads();
    for (int i = t; i < n; i += 256)
        esrc[base + i] = sortbuf[i];
}

// ---------------- weight prep (all three, one launch) ----------------

__global__ void k_prepW(const float* __restrict__ W1, const float* __restrict__ W2,
                        const float* __restrict__ Wo, ushort* __restrict__ W1s,
                        ushort* __restrict__ W2s, ushort* __restrict__ WoTs) {
    int i = blockIdx.x * blockDim.x + threadIdx.x;  // 0..40959
    if (i < 16384) {
        int k = i >> 7, n = i & 127;
        W1s[swz(n, k)] = f2h(W1[i]);
    } else if (i < 32768) {
        int j = i - 16384, k = j >> 7, n = j & 127;
        W2s[swz(n, k)] = f2h(W2[j]);
    } else if (i < 40960) {
        int j = i - 32768, k = j >> 6, n = j & 63;
        WoTs[swz(n, k)] = f2h(Wo[j]);
    }
}

// ---------------- MFMA GEMM: out_f16[r] = dis[r] * (A[r] @ W) (r6-proven) ----------------

template <typename IT>
__global__ __launch_bounds__(256) void k_gemm_mfma(const IT* __restrict__ A,
                                                   const ushort* __restrict__ Ws,
                                                   const float* __restrict__ dis,
                                                   ushort* __restrict__ out) {
    __shared__ ushort sB[128 * 128];
    __shared__ ushort sA[64 * 128];
    const int tid = threadIdx.x;
    const int row0 = blockIdx.x * 64;

    for (int i = tid; i < 2048; i += 256)
        ((float4*)sB)[i] = ((const float4*)Ws)[i];

    for (int i = tid; i < 2048; i += 256) {
        int m = i >> 5, u = i & 31, k4 = u << 2;
        int r = row0 + m;
        ushort4 pk = make_ushort4(0, 0, 0, 0);
        if (r < N_NODES) {
            if constexpr (sizeof(IT) == 4) {
                float4 a = ((const float4*)A)[r * 32 + u];
                pk = make_ushort4(f2h(a.x), f2h(a.y), f2h(a.z), f2h(a.w));
            } else {
                pk = ((const ushort4*)A)[r * 32 + u];
            }
        }
        *(ushort4*)&sA[swz(m, k4)] = pk;
    }
    __syncthreads();

    const int lane = tid & 63, wv = tid >> 6;
    const int mrow = lane & 15, quad = lane >> 4;
    f32x4 acc[8] = {};
#pragma unroll
    for (int kc = 0; kc < 4; ++kc) {
        int g = kc * 4 + quad;
        half8 a = *(const half8*)&sA[(wv * 16 + mrow) * 128 + ((g ^ mrow) << 3)];
#pragma unroll
        for (int nt = 0; nt < 8; ++nt) {
            half8 b = *(const half8*)&sB[(nt * 16 + mrow) * 128 + ((g ^ mrow) << 3)];
            acc[nt] = __builtin_amdgcn_mfma_f32_16x16x32_f16(a, b, acc[nt], 0, 0, 0);
        }
    }

    const int rbase = row0 + wv * 16 + quad * 4;
    float ds[4];
#pragma unroll
    for (int rg = 0; rg < 4; ++rg)
        ds[rg] = (rbase + rg < N_NODES) ? dis[rbase + rg] : 0.f;
#pragma unroll
    for (int nt = 0; nt < 8; ++nt) {
#pragma unroll
        for (int rg = 0; rg < 4; ++rg) {
            int r = rbase + rg;
            if (r < N_NODES) out[r * 128 + nt * 16 + mrow] = f2h(acc[nt][rg] * ds[rg]);
        }
    }
}

// ---------------- CSR aggregation (r6 core, unroll-8 / 4 acc pairs) ----------------
// out[v] = relu(dis[v] * (sum_e h'[src_e] + h'[v]) + bias), fp16 pk accumulate.
// One wave per node; half-wave per edge; 8 edges in flight per half.

__global__ __launch_bounds__(256) void k_agg(const int* __restrict__ start,
                                             const int* __restrict__ cnt,
                                             const int* __restrict__ esrc,
                                             const ushort* __restrict__ h,
                                             const float* __restrict__ dis,
                                             const float* __restrict__ bias,
                                             ushort* __restrict__ out) {
    const int v = blockIdx.x * 4 + (threadIdx.x >> 6);
    const int lane = threadIdx.x & 63, half = lane >> 5, l = lane & 31;
    const uint2* h4 = (const uint2*)h;

    int n = cnt[v];
    const int* ep = esrc + start[v];

    uint2 aA = make_uint2(0, 0), aB = make_uint2(0, 0);
    uint2 aC = make_uint2(0, 0), aD = make_uint2(0, 0);
    int i = half;
    for (; i + 14 < n; i += 16) {  // this half: 8 edges i, i+2, ..., i+14
        int s0 = ep[i], s1 = ep[i + 2], s2 = ep[i + 4], s3 = ep[i + 6];
        int s4 = ep[i + 8], s5 = ep[i + 10], s6 = ep[i + 12], s7 = ep[i + 14];
        uint2 t0 = h4[s0 * 32 + l];
        uint2 t1 = h4[s1 * 32 + l];
        uint2 t2 = h4[s2 * 32 + l];
        uint2 t3 = h4[s3 * 32 + l];
        uint2 t4 = h4[s4 * 32 + l];
        uint2 t5 = h4[s5 * 32 + l];
        uint2 t6 = h4[s6 * 32 + l];
        uint2 t7 = h4[s7 * 32 + l];
        aA.x = pkadd(aA.x, t0.x); aA.y = pkadd(aA.y, t0.y);
        aB.x = pkadd(aB.x, t1.x); aB.y = pkadd(aB.y, t1.y);
        aC.x = pkadd(aC.x, t2.x); aC.y = pkadd(aC.y, t2.y);
        aD.x = pkadd(aD.x, t3.x); aD.y = pkadd(aD.y, t3.y);
        aA.x = pkadd(aA.x, t4.x); aA.y = pkadd(aA.y, t4.y);
        aB.x = pkadd(aB.x, t5.x); aB.y = pkadd(aB.y, t5.y);
        aC.x = pkadd(aC.x, t6.x); aC.y = pkadd(aC.y, t6.y);
        aD.x = pkadd(aD.x, t7.x); aD.y = pkadd(aD.y, t7.y);
    }
    for (; i + 6 < n; i += 8) {  // 4 edges
        int s0 = ep[i], s1 = ep[i + 2], s2 = ep[i + 4], s3 = ep[i + 6];
        uint2 t0 = h4[s0 * 32 + l];
        uint2 t1 = h4[s1 * 32 + l];
        uint2 t2 = h4[s2 * 32 + l];
        uint2 t3 = h4[s3 * 32 + l];
        aA.x = pkadd(aA.x, t0.x); aA.y = pkadd(aA.y, t0.y);
        aB.x = pkadd(aB.x, t1.x); aB.y = pkadd(aB.y, t1.y);
        aC.x = pkadd(aC.x, t2.x); aC.y = pkadd(aC.y, t2.y);
        aD.x = pkadd(aD.x, t3.x); aD.y = pkadd(aD.y, t3.y);
    }
    for (; i < n; i += 2) {
        int s0 = ep[i];
        uint2 t0 = h4[s0 * 32 + l];
        aA.x = pkadd(aA.x, t0.x); aA.y = pkadd(aA.y, t0.y);
    }
    aA.x = pkadd(aA.x, aB.x); aA.y = pkadd(aA.y, aB.y);
    aC.x = pkadd(aC.x, aD.x); aC.y = pkadd(aC.y, aD.y);
    aA.x = pkadd(aA.x, aC.x); aA.y = pkadd(aA.y, aC.y);
    // combine halves
    aA.x = pkadd(aA.x, (uint)__shfl_xor((int)aA.x, 32));
    aA.y = pkadd(aA.y, (uint)__shfl_xor((int)aA.y, 32));

    if (half == 0) {
        uint2 hv = h4[v * 32 + l];  // self-loop term h'[v]
        aA.x = pkadd(aA.x, hv.x);
        aA.y = pkadd(aA.y, hv.y);
        float s = dis[v];
        float2 a0 = __half22float2(*(__half2*)&aA.x);
        float2 a1 = __half22float2(*(__half2*)&aA.y);
        float4 bv = *(const float4*)&bias[l * 4];
        a0.x = fmaxf(a0.x * s + bv.x, 0.f);
        a0.y = fmaxf(a0.y * s + bv.y, 0.f);
        a1.x = fmaxf(a1.x * s + bv.z, 0.f);
        a1.y = fmaxf(a1.y * s + bv.w, 0.f);
        __half2 o0 = __float22half2_rn(make_float2(a0.x, a0.y));
        __half2 o1 = __float22half2_rn(make_float2(a1.x, a1.y));
        ((uint2*)out)[v * 32 + l] = make_uint2(*(uint*)&o0, *(uint*)&o1);
    }
}

// ---------------- final MFMA: out_f32[N][64] = (x1+x2)@Wo + bo (r6-proven) ----------------

__global__ __launch_bounds__(256) void k_final_mfma(const ushort* __restrict__ x1,
                                                    const ushort* __restrict__ x2,
                                                    const ushort* __restrict__ Ws,
                                                    const float* __restrict__ bo,
                                                    float* __restrict__ out) {
    __shared__ ushort sB[64 * 128];
    __shared__ ushort sA[64 * 128];
    const int tid = threadIdx.x;
    const int row0 = blockIdx.x * 64;

    for (int i = tid; i < 1024; i += 256)
        ((float4*)sB)[i] = ((const float4*)Ws)[i];

    for (int i = tid; i < 2048; i += 256) {
        int m = i >> 5, u = i & 31, k4 = u << 2;
        int r = row0 + m;
        uint2 pk = make_uint2(0, 0);
        if (r < N_NODES) {
            uint2 ua = ((const uint2*)x1)[r * 32 + u];
            uint2 ub = ((const uint2*)x2)[r * 32 + u];
            __half2 s0 = __hadd2(*(__half2*)&ua.x, *(__half2*)&ub.x);
            __half2 s1 = __hadd2(*(__half2*)&ua.y, *(__half2*)&ub.y);
            pk = make_uint2(*(uint*)&s0, *(uint*)&s1);
        }
        *(uint2*)&sA[swz(m, k4)] = pk;
    }
    __syncthreads();

    const int lane = tid & 63, wv = tid >> 6;
    const int mrow = lane & 15, quad = lane >> 4;
    f32x4 acc[4] = {};
#pragma unroll
    for (int kc = 0; kc < 4; ++kc) {
        int g = kc * 4 + quad;
        half8 a = *(const half8*)&sA[(wv * 16 + mrow) * 128 + ((g ^ mrow) << 3)];
#pragma unroll
        for (int nt = 0; nt < 4; ++nt) {
            half8 b = *(const half8*)&sB[(nt * 16 + mrow) * 128 + ((g ^ mrow) << 3)];
            acc[nt] = __builtin_amdgcn_mfma_f32_16x16x32_f16(a, b, acc[nt], 0, 0, 0);
        }
    }

    const int rbase = row0 + wv * 16 + quad * 4;
#pragma unroll
    for (int nt = 0; nt < 4; ++nt) {
        float bb = bo[nt * 16 + mrow];
#pragma unroll
        for (int rg = 0; rg < 4; ++rg) {
            int r = rbase + rg;
            if (r < N_NODES) out[(size_t)r * 64 + nt * 16 + mrow] = acc[nt][rg] + bb;
        }
    }
}

// ---------------- launch ----------------

extern "C" void kernel_launch(void* const* d_in, const int* in_sizes, int n_in,
                              void* d_out, int out_size, void* d_ws, size_t ws_size,
                              hipStream_t stream) {
    const float* x  = (const float*)d_in[0];
    const int*   ei = (const int*)d_in[1];
    const int*   src = ei;
    const int*   dst = ei + N_EDGES;
    const float* W1 = (const float*)d_in[2];
    const float* b1 = (const float*)d_in[3];
    const float* W2 = (const float*)d_in[4];
    const float* b2 = (const float*)d_in[5];
    const float* Wo = (const float*)d_in[6];
    const float* bo = (const float*)d_in[7];
    float* out = (float*)d_out;

    char* ws = (char*)d_ws;
    int*    bfill  = (int*)ws;            ws += 2048;
    int*    cnt    = (int*)ws;            ws += 400000;
    int*    start  = (int*)ws;            ws += 400000;
    float*  dis    = (float*)ws;          ws += 400000;
    int*    bin    = (int*)ws;            ws += (size_t)NBUCKET * CAP * 4;  // 7.2 MB
    int*    esrc   = (int*)ws;            ws += (size_t)N_EDGES * 4;
    ushort* W1s    = (ushort*)ws;         ws += 32768;
    ushort* W2s    = (ushort*)ws;         ws += 32768;
    ushort* WoTs   = (ushort*)ws;         ws += 16384;
    ushort* h      = (ushort*)ws;         ws += (size_t)N_NODES * CH * 2;
    ushort* x1     = (ushort*)ws;         ws += (size_t)N_NODES * CH * 2;
    ushort* x2     = (ushort*)ws;

    const int B = 256;
    const int gG = (N_NODES + 63) / 64;   // 1563

    // CSR build (LDS-staged counting sort) + weight prep
    hipMemsetAsync(bfill, 0, 512, stream);
    k_bin<<<(N_EDGES + BIN_CHUNK - 1) / BIN_CHUNK, 512, 0, stream>>>(src, dst, bfill, bin);
    k_build<<<NBUCKET, 256, 0, stream>>>(bfill, bin, esrc, start, cnt, dis);
    k_prepW<<<160, B, 0, stream>>>(W1, W2, Wo, W1s, W2s, WoTs);

    // layer 1
    k_gemm_mfma<float><<<gG, B, 0, stream>>>(x, W1s, dis, h);
    k_agg<<<N_NODES / 4, B, 0, stream>>>(start, cnt, esrc, h, dis, b1, x1);

    // layer 2
    k_gemm_mfma<ushort><<<gG, B, 0, stream>>>(x1, W2s, dis, h);
    k_agg<<<N_NODES / 4, B, 0, stream>>>(start, cnt, esrc, h, dis, b2, x2);

    // output projection
    k_final_mfma<<<gG, B, 0, stream>>>(x1, x2, WoTs, bo, out);
}

// Round 10
// 332.376 us; speedup vs baseline: 2.2164x; 1.0732x over previous
//
#include <hip/hip_runtime.h>
#include <hip/hip_fp16.h>

#define N_NODES 100000
#define N_EDGES 1600000
#define CH 128
#define OCH 64
#define NBUCKET 391   // ceil(100000/256) dst-buckets of 256 nodes
#define CAP 8192      // bucket capacity (mean 4092, sd ~64)
#define BIN_CHUNK 4096

typedef _Float16 half8 __attribute__((ext_vector_type(8)));
typedef float f32x4 __attribute__((ext_vector_type(4)));

__device__ __forceinline__ ushort f2h(float f) {
    _Float16 h = (_Float16)f;
    return *(ushort*)&h;
}

__device__ __forceinline__ uint pkadd(uint a, uint b) {
    __half2 r = __hadd2(*(__half2*)&a, *(__half2*)&b);
    return *(uint*)&r;
}

// XOR-swizzled f16 offset inside a [rows][128] f16 tile (r6-proven, 0 conflicts).
__device__ __forceinline__ int swz(int row, int k) {
    return row * 128 + ((((k >> 3) ^ (row & 15)) << 3) | (k & 7));
}

// ---------------- CSR build: LDS-staged counting sort (r6-proven shape) ----------------

__global__ __launch_bounds__(512) void k_bin(const int* __restrict__ src,
                                             const int* __restrict__ dst,
                                             int* __restrict__ bfill,
                                             int* __restrict__ bin) {
    __shared__ int hist[512];
    __shared__ int wbase[512];
    __shared__ int cur[512];
    const int t = threadIdx.x;
    const int e0 = blockIdx.x * BIN_CHUNK;

    hist[t] = 0;
    __syncthreads();

    int ss[8], bb[8], dl[8];
#pragma unroll
    for (int j = 0; j < 8; ++j) {
        int e = e0 + j * 512 + t;
        bb[j] = -1;
        if (e < N_EDGES) {
            int s = src[e], d = dst[e];
            ss[j] = s; dl[j] = d & 255; bb[j] = d >> 8;
            atomicAdd(&hist[bb[j]], 1);
        }
    }
    __syncthreads();

    int v = hist[t];
    for (int off = 1; off < 512; off <<= 1) {
        int tv = (t >= off) ? hist[t - off] : 0;
        __syncthreads();
        hist[t] += tv;
        __syncthreads();
    }
    int excl = hist[t] - v;
    if (t < NBUCKET && v > 0) {
        int gb = atomicAdd(&bfill[t], v);
        wbase[t] = gb - excl;
    }
    cur[t] = excl;
    __syncthreads();

#pragma unroll
    for (int j = 0; j < 8; ++j) {
        if (bb[j] >= 0) {
            int p = atomicAdd(&cur[bb[j]], 1);
            bin[bb[j] * CAP + wbase[bb[j]] + p] = (ss[j] << 8) | dl[j];
        }
    }
}

// block 0: exclusive scan of bucket fills. blocks 1..80: weight prep (fused launch).
__global__ __launch_bounds__(512) void k_scan_prep(const int* __restrict__ bfill,
                                                   int* __restrict__ bbase,
                                                   const float* __restrict__ W1,
                                                   const float* __restrict__ W2,
                                                   const float* __restrict__ Wo,
                                                   ushort* __restrict__ W1s,
                                                   ushort* __restrict__ W2s,
                                                   ushort* __restrict__ WoTs) {
    if (blockIdx.x == 0) {
        __shared__ int tmp[512];
        int t = threadIdx.x;
        int v = (t < NBUCKET) ? bfill[t] : 0;
        tmp[t] = v;
        __syncthreads();
        for (int off = 1; off < 512; off <<= 1) {
            int tv = (t >= off) ? tmp[t - off] : 0;
            __syncthreads();
            tmp[t] += tv;
            __syncthreads();
        }
        if (t < NBUCKET) bbase[t] = tmp[t] - v;
    } else {
        int i = (blockIdx.x - 1) * 512 + threadIdx.x;  // 0..40959
        if (i < 16384) {
            int k = i >> 7, n = i & 127;
            W1s[swz(n, k)] = f2h(W1[i]);
        } else if (i < 32768) {
            int j = i - 16384, k = j >> 7, n = j & 127;
            W2s[swz(n, k)] = f2h(W2[j]);
        } else if (i < 40960) {
            int j = i - 32768, k = j >> 6, n = j & 63;
            WoTs[swz(n, k)] = f2h(Wo[j]);
        }
    }
}

__global__ __launch_bounds__(256) void k_build(const int* __restrict__ bfill,
                                               const int* __restrict__ bbase,
                                               const int* __restrict__ bin,
                                               int* __restrict__ esrc,
                                               int* __restrict__ start,
                                               int* __restrict__ cnt,
                                               float* __restrict__ dis) {
    __shared__ int cnt_l[256];
    __shared__ int cur_l[256];
    __shared__ int sortbuf[CAP];
    const int t = threadIdx.x;
    const int b = blockIdx.x;
    const int n = bfill[b];
    const int base = bbase[b];
    const int* brec = bin + b * CAP;

    cnt_l[t] = 0;
    __syncthreads();
    for (int i = t; i < n; i += 256)
        atomicAdd(&cnt_l[brec[i] & 255], 1);
    __syncthreads();

    int v = cnt_l[t];
    for (int off = 1; off < 256; off <<= 1) {
        int tv = (t >= off) ? cnt_l[t - off] : 0;
        __syncthreads();
        cnt_l[t] += tv;
        __syncthreads();
    }
    int excl = cnt_l[t] - v;
    int node = b * 256 + t;
    if (node < N_NODES) {
        start[node] = base + excl;
        cnt[node] = v;
        dis[node] = rsqrtf((float)(v + 1));  // +1 self-loop
    }
    cur_l[t] = excl;
    __syncthreads();

    for (int i = t; i < n; i += 256) {
        int rec = brec[i];
        int p = atomicAdd(&cur_l[rec & 255], 1);
        sortbuf[p] = rec >> 8;
    }
    __syncthreads();
    for (int i = t; i < n; i += 256)
        esrc[base + i] = sortbuf[i];
}

// ---------------- MFMA GEMM: out_f16[r] = dis[r] * (A[r] @ W) (r6-proven) ----------------

template <typename IT>
__global__ __launch_bounds__(256) void k_gemm_mfma(const IT* __restrict__ A,
                                                   const ushort* __restrict__ Ws,
                                                   const float* __restrict__ dis,
                                                   ushort* __restrict__ out) {
    __shared__ ushort sB[128 * 128];
    __shared__ ushort sA[64 * 128];
    const int tid = threadIdx.x;
    const int row0 = blockIdx.x * 64;

    for (int i = tid; i < 2048; i += 256)
        ((float4*)sB)[i] = ((const float4*)Ws)[i];

    for (int i = tid; i < 2048; i += 256) {
        int m = i >> 5, u = i & 31, k4 = u << 2;
        int r = row0 + m;
        ushort4 pk = make_ushort4(0, 0, 0, 0);
        if (r < N_NODES) {
            if constexpr (sizeof(IT) == 4) {
                float4 a = ((const float4*)A)[r * 32 + u];
                pk = make_ushort4(f2h(a.x), f2h(a.y), f2h(a.z), f2h(a.w));
            } else {
                pk = ((const ushort4*)A)[r * 32 + u];
            }
        }
        *(ushort4*)&sA[swz(m, k4)] = pk;
    }
    __syncthreads();

    const int lane = tid & 63, wv = tid >> 6;
    const int mrow = lane & 15, quad = lane >> 4;
    f32x4 acc[8] = {};
#pragma unroll
    for (int kc = 0; kc < 4; ++kc) {
        int g = kc * 4 + quad;
        half8 a = *(const half8*)&sA[(wv * 16 + mrow) * 128 + ((g ^ mrow) << 3)];
#pragma unroll
        for (int nt = 0; nt < 8; ++nt) {
            half8 b = *(const half8*)&sB[(nt * 16 + mrow) * 128 + ((g ^ mrow) << 3)];
            acc[nt] = __builtin_amdgcn_mfma_f32_16x16x32_f16(a, b, acc[nt], 0, 0, 0);
        }
    }

    const int rbase = row0 + wv * 16 + quad * 4;
    float ds[4];
#pragma unroll
    for (int rg = 0; rg < 4; ++rg)
        ds[rg] = (rbase + rg < N_NODES) ? dis[rbase + rg] : 0.f;
#pragma unroll
    for (int nt = 0; nt < 8; ++nt) {
#pragma unroll
        for (int rg = 0; rg < 4; ++rg) {
            int r = rbase + rg;
            if (r < N_NODES) out[r * 128 + nt * 16 + mrow] = f2h(acc[nt][rg] * ds[rg]);
        }
    }
}

// ---------------- CSR aggregation: uint4 loads, quarter-wave per edge ----------------
// out[v] = relu(dis[v] * (sum_e h'[src_e] + h'[v]) + bias), fp16 pk accumulate.
// One wave per node; 16 lanes per edge row (16B/lane); 4 edges/load-instr,
// 4 loads in flight per quarter (16 edges/wave outstanding).

__global__ __launch_bounds__(256) void k_agg(const int* __restrict__ start,
                                             const int* __restrict__ cnt,
                                             const int* __restrict__ esrc,
                                             const ushort* __restrict__ h,
                                             const float* __restrict__ dis,
                                             const float* __restrict__ bias,
                                             ushort* __restrict__ out) {
    const int v = blockIdx.x * 4 + (threadIdx.x >> 6);
    const int lane = threadIdx.x & 63, q = lane >> 4, l = lane & 15;
    const uint4* h16 = (const uint4*)h;

    int n = cnt[v];
    const int* ep = esrc + start[v];

    uint4 aA = make_uint4(0, 0, 0, 0), aB = make_uint4(0, 0, 0, 0);
    int i = q;
    for (; i + 12 < n; i += 16) {  // this quarter: edges i, i+4, i+8, i+12
        int s0 = ep[i], s1 = ep[i + 4], s2 = ep[i + 8], s3 = ep[i + 12];
        uint4 t0 = h16[s0 * 16 + l];
        uint4 t1 = h16[s1 * 16 + l];
        uint4 t2 = h16[s2 * 16 + l];
        uint4 t3 = h16[s3 * 16 + l];
        aA.x = pkadd(aA.x, t0.x); aA.y = pkadd(aA.y, t0.y);
        aA.z = pkadd(aA.z, t0.z); aA.w = pkadd(aA.w, t0.w);
        aB.x = pkadd(aB.x, t1.x); aB.y = pkadd(aB.y, t1.y);
        aB.z = pkadd(aB.z, t1.z); aB.w = pkadd(aB.w, t1.w);
        aA.x = pkadd(aA.x, t2.x); aA.y = pkadd(aA.y, t2.y);
        aA.z = pkadd(aA.z, t2.z); aA.w = pkadd(aA.w, t2.w);
        aB.x = pkadd(aB.x, t3.x); aB.y = pkadd(aB.y, t3.y);
        aB.z = pkadd(aB.z, t3.z); aB.w = pkadd(aB.w, t3.w);
    }
    for (; i < n; i += 4) {
        int s0 = ep[i];
        uint4 t0 = h16[s0 * 16 + l];
        aA.x = pkadd(aA.x, t0.x); aA.y = pkadd(aA.y, t0.y);
        aA.z = pkadd(aA.z, t0.z); aA.w = pkadd(aA.w, t0.w);
    }
    aA.x = pkadd(aA.x, aB.x); aA.y = pkadd(aA.y, aB.y);
    aA.z = pkadd(aA.z, aB.z); aA.w = pkadd(aA.w, aB.w);
    // reduce across the 4 quarters
    aA.x = pkadd(aA.x, (uint)__shfl_xor((int)aA.x, 16));
    aA.y = pkadd(aA.y, (uint)__shfl_xor((int)aA.y, 16));
    aA.z = pkadd(aA.z, (uint)__shfl_xor((int)aA.z, 16));
    aA.w = pkadd(aA.w, (uint)__shfl_xor((int)aA.w, 16));
    aA.x = pkadd(aA.x, (uint)__shfl_xor((int)aA.x, 32));
    aA.y = pkadd(aA.y, (uint)__shfl_xor((int)aA.y, 32));
    aA.z = pkadd(aA.z, (uint)__shfl_xor((int)aA.z, 32));
    aA.w = pkadd(aA.w, (uint)__shfl_xor((int)aA.w, 32));

    if (q == 0) {
        uint4 hv = h16[v * 16 + l];  // self-loop term h'[v]
        aA.x = pkadd(aA.x, hv.x); aA.y = pkadd(aA.y, hv.y);
        aA.z = pkadd(aA.z, hv.z); aA.w = pkadd(aA.w, hv.w);
        float s = dis[v];
        float2 a0 = __half22float2(*(__half2*)&aA.x);
        float2 a1 = __half22float2(*(__half2*)&aA.y);
        float2 a2 = __half22float2(*(__half2*)&aA.z);
        float2 a3 = __half22float2(*(__half2*)&aA.w);
        float4 b0 = ((const float4*)bias)[2 * l];
        float4 b1 = ((const float4*)bias)[2 * l + 1];
        a0.x = fmaxf(a0.x * s + b0.x, 0.f); a0.y = fmaxf(a0.y * s + b0.y, 0.f);
        a1.x = fmaxf(a1.x * s + b0.z, 0.f); a1.y = fmaxf(a1.y * s + b0.w, 0.f);
        a2.x = fmaxf(a2.x * s + b1.x, 0.f); a2.y = fmaxf(a2.y * s + b1.y, 0.f);
        a3.x = fmaxf(a3.x * s + b1.z, 0.f); a3.y = fmaxf(a3.y * s + b1.w, 0.f);
        __half2 o0 = __float22half2_rn(a0);
        __half2 o1 = __float22half2_rn(a1);
        __half2 o2 = __float22half2_rn(a2);
        __half2 o3 = __float22half2_rn(a3);
        ((uint4*)out)[v * 16 + l] =
            make_uint4(*(uint*)&o0, *(uint*)&o1, *(uint*)&o2, *(uint*)&o3);
    }
}

// ---------------- final MFMA: out_f32[N][64] = (x1+x2)@Wo + bo (r6-proven) ----------------

__global__ __launch_bounds__(256) void k_final_mfma(const ushort* __restrict__ x1,
                                                    const ushort* __restrict__ x2,
                                                    const ushort* __restrict__ Ws,
                                                    const float* __restrict__ bo,
                                                    float* __restrict__ out) {
    __shared__ ushort sB[64 * 128];
    __shared__ ushort sA[64 * 128];
    const int tid = threadIdx.x;
    const int row0 = blockIdx.x * 64;

    for (int i = tid; i < 1024; i += 256)
        ((float4*)sB)[i] = ((const float4*)Ws)[i];

    for (int i = tid; i < 2048; i += 256) {
        int m = i >> 5, u = i & 31, k4 = u << 2;
        int r = row0 + m;
        uint2 pk = make_uint2(0, 0);
        if (r < N_NODES) {
            uint2 ua = ((const uint2*)x1)[r * 32 + u];
            uint2 ub = ((const uint2*)x2)[r * 32 + u];
            __half2 s0 = __hadd2(*(__half2*)&ua.x, *(__half2*)&ub.x);
            __half2 s1 = __hadd2(*(__half2*)&ua.y, *(__half2*)&ub.y);
            pk = make_uint2(*(uint*)&s0, *(uint*)&s1);
        }
        *(uint2*)&sA[swz(m, k4)] = pk;
    }
    __syncthreads();

    const int lane = tid & 63, wv = tid >> 6;
    const int mrow = lane & 15, quad = lane >> 4;
    f32x4 acc[4] = {};
#pragma unroll
    for (int kc = 0; kc < 4; ++kc) {
        int g = kc * 4 + quad;
        half8 a = *(const half8*)&sA[(wv * 16 + mrow) * 128 + ((g ^ mrow) << 3)];
#pragma unroll
        for (int nt = 0; nt < 4; ++nt) {
            half8 b = *(const half8*)&sB[(nt * 16 + mrow) * 128 + ((g ^ mrow) << 3)];
            acc[nt] = __builtin_amdgcn_mfma_f32_16x16x32_f16(a, b, acc[nt], 0, 0, 0);
        }
    }

    const int rbase = row0 + wv * 16 + quad * 4;
#pragma unroll
    for (int nt = 0; nt < 4; ++nt) {
        float bb = bo[nt * 16 + mrow];
#pragma unroll
        for (int rg = 0; rg < 4; ++rg) {
            int r = rbase + rg;
            if (r < N_NODES) out[(size_t)r * 64 + nt * 16 + mrow] = acc[nt][rg] + bb;
        }
    }
}

// ---------------- launch ----------------

extern "C" void kernel_launch(void* const* d_in, const int* in_sizes, int n_in,
                              void* d_out, int out_size, void* d_ws, size_t ws_size,
                              hipStream_t stream) {
    const float* x  = (const float*)d_in[0];
    const int*   ei = (const int*)d_in[1];
    const int*   src = ei;
    const int*   dst = ei + N_EDGES;
    const float* W1 = (const float*)d_in[2];
    const float* b1 = (const float*)d_in[3];
    const float* W2 = (const float*)d_in[4];
    const float* b2 = (const float*)d_in[5];
    const float* Wo = (const float*)d_in[6];
    const float* bo = (const float*)d_in[7];
    float* out = (float*)d_out;

    char* ws = (char*)d_ws;
    int*    bfill  = (int*)ws;            ws += 2048;
    int*    bbase  = (int*)ws;            ws += 2048;
    int*    cnt    = (int*)ws;            ws += 400000;
    int*    start  = (int*)ws;            ws += 400000;
    float*  dis    = (float*)ws;          ws += 400000;
    int*    bin    = (int*)ws;            ws += (size_t)NBUCKET * CAP * 4;  // 12.8 MB
    int*    esrc   = (int*)ws;            ws += (size_t)N_EDGES * 4;
    ushort* W1s    = (ushort*)ws;         ws += 32768;
    ushort* W2s    = (ushort*)ws;         ws += 32768;
    ushort* WoTs   = (ushort*)ws;         ws += 16384;
    ushort* h      = (ushort*)ws;         ws += (size_t)N_NODES * CH * 2;
    ushort* x1     = (ushort*)ws;         ws += (size_t)N_NODES * CH * 2;
    ushort* x2     = (ushort*)ws;

    const int B = 256;
    const int gG = (N_NODES + 63) / 64;   // 1563

    // CSR build (LDS-staged counting sort) + weight prep
    hipMemsetAsync(bfill, 0, 2048, stream);
    k_bin<<<(N_EDGES + BIN_CHUNK - 1) / BIN_CHUNK, 512, 0, stream>>>(src, dst, bfill, bin);
    k_scan_prep<<<81, 512, 0, stream>>>(bfill, bbase, W1, W2, Wo, W1s, W2s, WoTs);
    k_build<<<NBUCKET, 256, 0, stream>>>(bfill, bbase, bin, esrc, start, cnt, dis);

    // layer 1
    k_gemm_mfma<float><<<gG, B, 0, stream>>>(x, W1s, dis, h);
    k_agg<<<N_NODES / 4, B, 0, stream>>>(start, cnt, esrc, h, dis, b1, x1);

    // layer 2
    k_gemm_mfma<ushort><<<gG, B, 0, stream>>>(x1, W2s, dis, h);
    k_agg<<<N_NODES / 4, B, 0, stream>>>(start, cnt, esrc, h, dis, b2, x2);

    // output projection
    k_final_mfma<<<gG, B, 0, stream>>>(x1, x2, WoTs, bo, out);
}